// Round 12
// baseline (973.382 us; speedup 1.0000x reference)
//
#include <hip/hip_runtime.h>
#include <math.h>

static inline int cdiv(int a, int b) { return (a + b - 1) / b; }

typedef __attribute__((ext_vector_type(8))) short short8;
typedef __attribute__((ext_vector_type(4))) float floatx4;
typedef unsigned short ushort4e __attribute__((ext_vector_type(4)));

#define HMAXN 30720   // static LDS table capacity (N=30000 fits; 122880 B < 160 KiB)
#define HB 128        // histogram / scatter blocks (identical edge slicing)

__device__ inline unsigned short f2bf(float f) {
    unsigned int u = __float_as_uint(f);
    unsigned int r = (u + 0x7fffu + ((u >> 16) & 1u)) >> 16;
    return (unsigned short)r;
}
__device__ inline float bf2f(unsigned short u) {
    return __uint_as_float(((unsigned int)u) << 16);
}

// ---------------- CSR build ----------------
// Packed histogram per node: (out_deg_excl_self << 16) | in_deg. Built in LDS per block
// (memory-side global atomics write-through ~32B each -> avoided), merged by streaming reduce.
// Scatter positions are then DETERMINISTIC: pos = off[b][d] + LDS-local rank, where
// off[b][d] = row_ptr[d] + sum_{b'<b} cnt_{b'}[d] -- no global atomics anywhere.

__global__ __launch_bounds__(256) void k_hist(const int* __restrict__ ei, int E, int N,
                                              int* __restrict__ partial) {
    __shared__ int h[HMAXN];
    for (int i = threadIdx.x; i < N; i += 256) h[i] = 0;
    __syncthreads();
    int per = (E + gridDim.x - 1) / gridDim.x;
    int beg = blockIdx.x * per;
    int end = beg + per; if (end > E) end = E;
    for (int e = beg + threadIdx.x; e < end; e += 256) {
        int s = ei[e], d = ei[E + e];
        atomicAdd(&h[d], 1);                       // in-degree (cnt)
        if (s != d) atomicAdd(&h[s], 0x10000);     // out-degree excluding self (deg)
    }
    __syncthreads();
    int* outp = partial + (size_t)blockIdx.x * N;
    for (int i = threadIdx.x; i < N; i += 256) outp[i] = h[i];
}

// fallback if N exceeds static LDS capacity (hist pre-zeroed by the launch-wide memset)
__global__ __launch_bounds__(256) void k_hist_glob(const int* __restrict__ ei, int E,
                                                   int* __restrict__ hist) {
    int e = blockIdx.x * 256 + threadIdx.x;
    if (e >= E) return;
    int s = ei[e], d = ei[E + e];
    atomicAdd(&hist[d], 1);
    if (s != d) atomicAdd(&hist[s], 0x10000);
}

__global__ __launch_bounds__(256) void k_hist_reduce(const int* __restrict__ partial,
                                                     int* __restrict__ hist, int N, int B) {
    int i = blockIdx.x * 256 + threadIdx.x;
    if (i >= N) return;
    int s = 0;
    for (int b = 0; b < B; b++) s += partial[(size_t)b * N + i];
    hist[i] = s;
}

// padded scan: each node's segment rounded up to a multiple of 8 (dummy edges are
// zero records from the memset -> src=0, norm=0.0 -> contribute exactly +0.0)
__global__ __launch_bounds__(1024) void k_scan(const int* __restrict__ hist, int* __restrict__ row_ptr,
                                               int N) {
    __shared__ int part[1024];
    int t = threadIdx.x;
    int chunk = (N + 1023) / 1024;
    int beg = t * chunk;
    int end = beg + chunk; if (end > N) end = N;
    int s = 0;
    for (int i = beg; i < end; i++) s += ((hist[i] & 0xffff) + 7) & ~7;
    part[t] = s;
    __syncthreads();
    for (int off = 1; off < 1024; off <<= 1) {
        int v = (t >= off) ? part[t - off] : 0;
        __syncthreads();
        part[t] += v;
        __syncthreads();
    }
    int base = (t > 0) ? part[t - 1] : 0;
    for (int i = beg; i < end; i++) { row_ptr[i] = base; base += ((hist[i] & 0xffff) + 7) & ~7; }
    if (t == 1023) row_ptr[N] = part[1023];
}

// per-(block,node) scatter base: off[b][i] = row_ptr[i] + sum_{b'<b} cnt_{b'}[i]
__global__ __launch_bounds__(256) void k_off(const int* __restrict__ partial,
                                             const int* __restrict__ row_ptr,
                                             int* __restrict__ off, int N, int B) {
    int i = blockIdx.x * 256 + threadIdx.x;
    if (i >= N) return;
    int run = row_ptr[i];
    for (int b = 0; b < B; b++) {
        off[(size_t)b * N + i] = run;
        run += partial[(size_t)b * N + i] & 0xffff;
    }
}

// atomic-free scatter: LDS-resident per-block offset table, LDS-atomic local ranks,
// single interleaved 8B record write per edge (1 dirty sector instead of 3).
__global__ __launch_bounds__(256) void k_scatter2(const int* __restrict__ ei, int E, int N,
                                                  const int* __restrict__ hist,
                                                  const int* __restrict__ off,
                                                  int2* __restrict__ erec, int Epad) {
    __shared__ int h[HMAXN];
    const int* offb = off + (size_t)blockIdx.x * N;
    for (int i = threadIdx.x; i < N; i += 256) h[i] = offb[i];
    __syncthreads();
    int per = (E + gridDim.x - 1) / gridDim.x;
    int beg = blockIdx.x * per;
    int end = beg + per; if (end > E) end = E;
    for (int e = beg + threadIdx.x; e < end; e += 256) {
        int s = ei[e], d = ei[E + e];
        float v = 0.f;
        if (s != d) {
            int a = hist[s] >> 16, b = hist[d] >> 16;
            float fa = (a > 0) ? 1.f / sqrtf((float)a) : 0.f;
            float fb = (b > 0) ? 1.f / sqrtf((float)b) : 0.f;
            v = -fa * fb;
        }
        int pos = atomicAdd(&h[d], 1);   // LDS atomic
        if (pos < Epad) erec[pos] = make_int2(s, __float_as_int(v));
    }
}

// fallback: global-atomic scatter (N > HMAXN)
__global__ __launch_bounds__(256) void k_scatter_glob(const int* __restrict__ ei, int E,
                                                      const int* __restrict__ hist,
                                                      const int* __restrict__ row_ptr,
                                                      int* __restrict__ fill,
                                                      int2* __restrict__ erec, int Epad) {
    int e = blockIdx.x * 256 + threadIdx.x;
    if (e >= E) return;
    int s = ei[e], d = ei[E + e];
    float v = 0.f;
    if (s != d) {
        int a = hist[s] >> 16, b = hist[d] >> 16;
        float fa = (a > 0) ? 1.f / sqrtf((float)a) : 0.f;
        float fb = (b > 0) ? 1.f / sqrtf((float)b) : 0.f;
        v = -fa * fb;
    }
    int pos = row_ptr[d] + atomicAdd(&fill[d], 1);
    if (pos < Epad) erec[pos] = make_int2(s, __float_as_int(v));
}

// -------- weight convert, all 6 layers in one dispatch (gridDim.y = layer) --------
// W[K][Cin][Cout] fp32 -> WT[Cout][K*256] bf16 (term-blocked, k zero-padded)

__global__ __launch_bounds__(256) void k_wconv6(const float* __restrict__ W0, const float* __restrict__ W1,
                                                const float* __restrict__ W2, const float* __restrict__ W3,
                                                const float* __restrict__ W4, const float* __restrict__ W5,
                                                unsigned short* __restrict__ T0, unsigned short* __restrict__ T1,
                                                unsigned short* __restrict__ T2, unsigned short* __restrict__ T3,
                                                unsigned short* __restrict__ T4, unsigned short* __restrict__ T5) {
    const int Cin[6]  = {128, 190, 256, 169, 190, 256};
    const int Cout[6] = {190, 256, 169, 190, 256, 128};
    const int Kt[6]   = {2, 2, 2, 5, 1, 3};
    const float* Ws[6] = {W0, W1, W2, W3, W4, W5};
    unsigned short* Ts[6] = {T0, T1, T2, T3, T4, T5};
    int li = blockIdx.y;
    int ldk = Kt[li] * 256;
    int total = Cout[li] * ldk;
    int idx = blockIdx.x * 256 + threadIdx.x;
    if (idx >= total) return;
    int n = idx / ldk;
    int rem = idx - n * ldk;
    int term = rem >> 8;
    int k = rem & 255;
    float v = (k < Cin[li]) ? Ws[li][(size_t)term * Cin[li] * Cout[li] + (size_t)k * Cout[li] + n] : 0.f;
    Ts[li][idx] = f2bf(v);
}

// ---------------- x (fp32, ld 128) -> wide bf16, stride 512, cols 0..127 ----------------

__global__ __launch_bounds__(128) void k_x0(const float* __restrict__ x, unsigned short* __restrict__ xb, int N) {
    int n = blockIdx.x;
    int c = threadIdx.x;
    xb[(size_t)n * 512 + c] = f2bf(x[(size_t)n * 128 + c]);
}

// ---------------- wave-per-node propagation (bf16 gather, fp32 accumulate) ----------------
// One node per GS-lane group (GS=64, or 32 when C4<=32). Lane = ushort4 channel slot.
// Edge records interleaved int2 (src, norm-bits); CSR segments padded to x8 -> aligned
// int4 record loads, 8 independent gathers in flight, no tail code.
// out[n][c] = sum_e norm_e * in[src_e][c]; if tm2*: r = 2*acc - tm2.
// in/outb/tm2b row stride ld4 (ushort4 units). outf/tm2f fp32 at stride 48 float4.

__global__ __launch_bounds__(256) void k_prop_w(const unsigned short* __restrict__ in,
                                                unsigned short* __restrict__ outb,
                                                float* __restrict__ outf,
                                                const unsigned short* __restrict__ tm2b,
                                                const float* __restrict__ tm2f,
                                                const int* __restrict__ row_ptr,
                                                const int2* __restrict__ erec,
                                                int C4, int Nn, int ld4, int gslog) {
    const int node = blockIdx.x * (256 >> gslog) + (threadIdx.x >> gslog);
    if (node >= Nn) return;
    const int lane4 = threadIdx.x & ((1 << gslog) - 1);
    if (lane4 >= C4) return;

    int beg = row_ptr[node], end = row_ptr[node + 1];
    const ushort4e* h4 = (const ushort4e*)in;
    float a0 = 0.f, a1 = 0.f, a2 = 0.f, a3 = 0.f;
    for (int j = beg; j < end; j += 8) {
        int4 r0 = *(const int4*)&erec[j];        // edges j, j+1
        int4 r1 = *(const int4*)&erec[j + 2];
        int4 r2 = *(const int4*)&erec[j + 4];
        int4 r3 = *(const int4*)&erec[j + 6];
        ushort4e v0 = h4[(size_t)r0.x * ld4 + lane4];
        ushort4e v1 = h4[(size_t)r0.z * ld4 + lane4];
        ushort4e v2 = h4[(size_t)r1.x * ld4 + lane4];
        ushort4e v3 = h4[(size_t)r1.z * ld4 + lane4];
        ushort4e v4 = h4[(size_t)r2.x * ld4 + lane4];
        ushort4e v5 = h4[(size_t)r2.z * ld4 + lane4];
        ushort4e v6 = h4[(size_t)r3.x * ld4 + lane4];
        ushort4e v7 = h4[(size_t)r3.z * ld4 + lane4];
        float n0 = __int_as_float(r0.y), n1 = __int_as_float(r0.w);
        float n2 = __int_as_float(r1.y), n3 = __int_as_float(r1.w);
        float n4 = __int_as_float(r2.y), n5 = __int_as_float(r2.w);
        float n6 = __int_as_float(r3.y), n7 = __int_as_float(r3.w);
        a0 += n0 * bf2f(v0.x) + n1 * bf2f(v1.x) + n2 * bf2f(v2.x) + n3 * bf2f(v3.x)
            + n4 * bf2f(v4.x) + n5 * bf2f(v5.x) + n6 * bf2f(v6.x) + n7 * bf2f(v7.x);
        a1 += n0 * bf2f(v0.y) + n1 * bf2f(v1.y) + n2 * bf2f(v2.y) + n3 * bf2f(v3.y)
            + n4 * bf2f(v4.y) + n5 * bf2f(v5.y) + n6 * bf2f(v6.y) + n7 * bf2f(v7.y);
        a2 += n0 * bf2f(v0.z) + n1 * bf2f(v1.z) + n2 * bf2f(v2.z) + n3 * bf2f(v3.z)
            + n4 * bf2f(v4.z) + n5 * bf2f(v5.z) + n6 * bf2f(v6.z) + n7 * bf2f(v7.z);
        a3 += n0 * bf2f(v0.w) + n1 * bf2f(v1.w) + n2 * bf2f(v2.w) + n3 * bf2f(v3.w)
            + n4 * bf2f(v4.w) + n5 * bf2f(v5.w) + n6 * bf2f(v6.w) + n7 * bf2f(v7.w);
    }
    if (tm2b) {
        ushort4e t = ((const ushort4e*)tm2b)[(size_t)node * ld4 + lane4];
        a0 = 2.f * a0 - bf2f(t.x); a1 = 2.f * a1 - bf2f(t.y);
        a2 = 2.f * a2 - bf2f(t.z); a3 = 2.f * a3 - bf2f(t.w);
    } else if (tm2f) {
        float4 t = ((const float4*)tm2f)[(size_t)node * 48 + lane4];
        a0 = 2.f * a0 - t.x; a1 = 2.f * a1 - t.y; a2 = 2.f * a2 - t.z; a3 = 2.f * a3 - t.w;
    }
    ushort4e r;
    r.x = f2bf(a0); r.y = f2bf(a1); r.z = f2bf(a2); r.w = f2bf(a3);
    ((ushort4e*)outb)[(size_t)node * ld4 + lane4] = r;
    if (outf) ((float4*)outf)[(size_t)node * 48 + lane4] = make_float4(a0, a1, a2, a3);
}

// ------- wide bf16 MFMA GEMM: A(bf16, lda) @ WT^T + bias -------
// If stats != null: write Y fp32 (stride 256) + fused column sum/sumsq.
// Else: fused ReLU, write bf16 to hb at stride ldo; cols in [Cout, tile-edge) zero-filled
// (downstream GEMM reading padded K-region must see exact zeros, not bf16-NaN garbage).
// BM=BN=128, BK=32; 4 waves in 2x2; each wave 64x64 as 4x4 frags of 16x16x32.

__global__ __launch_bounds__(256, 2) void k_gemm_w(const unsigned short* __restrict__ A, int lda,
                                                   const unsigned short* __restrict__ WT,
                                                   const float* __restrict__ bias,
                                                   float* __restrict__ Y,
                                                   float* __restrict__ stats,
                                                   unsigned short* __restrict__ hb, int ldo,
                                                   int M, int Kp, int Cout) {
    __shared__ unsigned short As[128][40];
    __shared__ unsigned short Bs[128][40];
    const int t = threadIdx.x;
    const int bm = blockIdx.y * 128, bn = blockIdx.x * 128;
    const int w = t >> 6, lane = t & 63;
    const int wr = w >> 1, wc = w & 1;
    const int fr = lane & 15, fg = lane >> 4;
    const int srow = t >> 2;
    const int skq = (t & 3) * 8;

    floatx4 acc[4][4];
#pragma unroll
    for (int i = 0; i < 4; i++)
#pragma unroll
        for (int j = 0; j < 4; j++) acc[i][j] = (floatx4){0.f, 0.f, 0.f, 0.f};

    for (int k0 = 0; k0 < Kp; k0 += 32) {
#pragma unroll
        for (int p = 0; p < 2; p++) {
            int r = p * 64 + srow;
            int grow = bm + r;
            uint4 av = make_uint4(0u, 0u, 0u, 0u);
            if (grow < M) av = *(const uint4*)&A[(size_t)grow * lda + k0 + skq];
            *(uint4*)&As[r][skq] = av;
            int gn = bn + r;
            uint4 bv = make_uint4(0u, 0u, 0u, 0u);
            if (gn < Cout) bv = *(const uint4*)&WT[(size_t)gn * lda + k0 + skq];
            *(uint4*)&Bs[r][skq] = bv;
        }
        __syncthreads();

        short8 a[4], b[4];
#pragma unroll
        for (int i = 0; i < 4; i++) a[i] = *(const short8*)&As[64 * wr + 16 * i + fr][fg * 8];
#pragma unroll
        for (int j = 0; j < 4; j++) b[j] = *(const short8*)&Bs[64 * wc + 16 * j + fr][fg * 8];
#pragma unroll
        for (int i = 0; i < 4; i++)
#pragma unroll
            for (int j = 0; j < 4; j++)
                acc[i][j] = __builtin_amdgcn_mfma_f32_16x16x32_bf16(a[i], b[j], acc[i][j], 0, 0, 0);
        __syncthreads();
    }

    // epilogue: C/D layout col=lane&15, row=(lane>>4)*4+q
    if (stats) {
        float s1[4] = {0.f, 0.f, 0.f, 0.f};
        float s2[4] = {0.f, 0.f, 0.f, 0.f};
#pragma unroll
        for (int j = 0; j < 4; j++) {
            int c = bn + 64 * wc + 16 * j + fr;
#pragma unroll
            for (int i = 0; i < 4; i++) {
#pragma unroll
                for (int q = 0; q < 4; q++) {
                    int r = bm + 64 * wr + 16 * i + fg * 4 + q;
                    float v = 0.f;
                    if (r < M && c < Cout) {
                        v = acc[i][j][q] + bias[c];
                        Y[(size_t)r * 256 + c] = v;
                    }
                    s1[j] += v;
                    s2[j] += v * v;
                }
            }
        }
#pragma unroll
        for (int j = 0; j < 4; j++) {
            s1[j] += __shfl_xor(s1[j], 16, 64);
            s1[j] += __shfl_xor(s1[j], 32, 64);
            s2[j] += __shfl_xor(s2[j], 16, 64);
            s2[j] += __shfl_xor(s2[j], 32, 64);
            if (fg == 0) {
                int c = bn + 64 * wc + 16 * j + fr;
                if (c < Cout) {
                    atomicAdd(&stats[c], s1[j]);
                    atomicAdd(&stats[256 + c], s2[j]);
                }
            }
        }
    } else {
        // fused ReLU -> bf16; zero-fill padding cols [Cout, tile-edge)
#pragma unroll
        for (int j = 0; j < 4; j++) {
            int c = bn + 64 * wc + 16 * j + fr;
            float bc = (c < Cout) ? bias[c] : 0.f;
#pragma unroll
            for (int i = 0; i < 4; i++) {
#pragma unroll
                for (int q = 0; q < 4; q++) {
                    int r = bm + 64 * wr + 16 * i + fg * 4 + q;
                    if (r < M) {
                        float v = (c < Cout) ? fmaxf(acc[i][j][q] + bc, 0.f) : 0.f;
                        hb[(size_t)r * ldo + c] = f2bf(v);
                    }
                }
            }
        }
    }
}

// ---------------- GraphNorm coeffs ----------------

__global__ __launch_bounds__(256) void k_coeffs(const float* __restrict__ stats,
                                                const float* __restrict__ w, const float* __restrict__ b,
                                                const float* __restrict__ ms,
                                                float* __restrict__ coeffs, int N, int C) {
    int c = threadIdx.x;
    if (c >= C) return;
    float m = stats[c] / (float)N;
    float q = stats[256 + c] / (float)N;
    float msv = ms[c];
    float v = q - m * m * msv * (2.f - msv);
    float sc = w[c] / sqrtf(v + 1e-5f);
    coeffs[c] = sc;
    coeffs[256 + c] = b[c] - sc * m * msv;
}

// leaky(0.2) + GraphNorm affine; reads Yb (fp32, stride 256), writes bf16 at out stride
__global__ __launch_bounds__(256) void k_act(const float* __restrict__ Y, unsigned short* __restrict__ hb,
                                             int ldo, const float* __restrict__ coeffs, int C) {
    int n = blockIdx.x;
    int c = threadIdx.x;
    if (c >= C) return;
    float v = Y[(size_t)n * 256 + c];
    v = v * coeffs[c] + coeffs[256 + c];
    v = (v > 0.f) ? v : 0.2f * v;
    hb[(size_t)n * ldo + c] = f2bf(v);
}

// ---------------- pooling (sorted batch -> segmented run reduction) + head ----------------

__global__ __launch_bounds__(128) void k_pool3(const unsigned short* __restrict__ hb, const int* __restrict__ batch,
                                               float* __restrict__ pooled, float* __restrict__ cntg, int N) {
    int t = threadIdx.x;
    int beg = blockIdx.x * 32;
    int end = beg + 32; if (end > N) end = N;
    if (beg >= N) return;
    int cur = batch[beg];
    float acc = 0.f;
    int runlen = 0;
    for (int n = beg; n < end; n++) {
        int b = batch[n];
        if (b != cur) {
            atomicAdd(&pooled[cur * 128 + t], acc);
            if (t == 0) atomicAdd(&cntg[cur], (float)runlen);
            acc = 0.f; runlen = 0; cur = b;
        }
        acc += bf2f(hb[(size_t)n * 256 + t]);
        runlen++;
    }
    atomicAdd(&pooled[cur * 128 + t], acc);
    if (t == 0) atomicAdd(&cntg[cur], (float)runlen);
}

__global__ __launch_bounds__(128) void k_head(const float* __restrict__ pooled, const float* __restrict__ cntg,
                                              const float* __restrict__ W1, const float* __restrict__ b1,
                                              const float* __restrict__ W2, const float* __restrict__ b2,
                                              float* __restrict__ out) {
    __shared__ float p[128];
    __shared__ float h1[64];
    int g = blockIdx.x;
    int t = threadIdx.x;
    float c = cntg[g];
    if (c < 1.f) c = 1.f;
    p[t] = pooled[g * 128 + t] / c;
    __syncthreads();
    if (t < 64) {
        float s = b1[t];
        for (int i = 0; i < 128; i++) s += p[i] * W1[i * 64 + t];
        h1[t] = tanhf(s);
    }
    __syncthreads();
    if (t < 10) {
        float s = b2[t];
        for (int i = 0; i < 64; i++) s += h1[i] * W2[i * 10 + t];
        out[g * 10 + t] = s;
    }
}

// ---------------- orchestration ----------------

extern "C" void kernel_launch(void* const* d_in, const int* in_sizes, int n_in,
                              void* d_out, int out_size, void* d_ws, size_t ws_size,
                              hipStream_t stream) {
    const float* x = (const float*)d_in[0];
    const int* ei = (const int*)d_in[1];
    const int* batch = (const int*)d_in[2];
    const float* convW[6]; const float* convB[6];
    for (int i = 0; i < 6; i++) { convW[i] = (const float*)d_in[3 + 2 * i]; convB[i] = (const float*)d_in[4 + 2 * i]; }
    const float* bnW[4]; const float* bnB[4]; const float* bnMS[4];
    for (int i = 0; i < 4; i++) { bnW[i] = (const float*)d_in[15 + 3 * i]; bnB[i] = (const float*)d_in[16 + 3 * i]; bnMS[i] = (const float*)d_in[17 + 3 * i]; }
    const float* lin1w = (const float*)d_in[27]; const float* lin1b = (const float*)d_in[28];
    const float* lin2w = (const float*)d_in[29]; const float* lin2b = (const float*)d_in[30];
    float* out = (float*)d_out;

    const int N = in_sizes[0] / 128;
    const int E = in_sizes[1] / 2;
    const int G = out_size / 10;
    const int Epad = E + 8 * N;   // worst-case padded CSR size (x8 rounding per node)

    struct LayerDef { int K, Cin, Cout, bn; };
    const LayerDef L[6] = {
        {2, 128, 190, 0},
        {2, 190, 256, 1},
        {2, 256, 169, 2},
        {5, 169, 190, -1},
        {1, 190, 256, -1},
        {3, 256, 128, 3},
    };
    const int stride[6] = {512, 512, 512, 1280, 256, 768};

    char* p = (char*)d_ws;
    auto alloc = [&](size_t bytes) -> void* { void* r = (void*)p; p += (bytes + 255) & ~(size_t)255; return r; };
    unsigned short* wide = (unsigned short*)alloc((size_t)N * 1280 * 2);  // all Chebyshev terms, bf16
    float* Yb  = (float*)alloc((size_t)N * 256 * 4);                      // GN-layer GEMM out; doubles as L4->L5 bf16 buf
    float* B1f = (float*)alloc((size_t)N * 192 * 4);                      // fp32 tm2 copies (layer 4)
    float* B2f = (float*)alloc((size_t)N * 192 * 4);
    // ---- contiguous zero-region (single memset at launch start) ----
    char* zbeg = p;
    int* fill = (int*)alloc((size_t)N * 4);                // used only by fallback path
    int2* erec = (int2*)alloc((size_t)Epad * 8);           // interleaved (src, norm) records
    float* stats4 = (float*)alloc(4 * 512 * 4);            // per-GN-layer stats slices
    float* pooled = (float*)alloc((size_t)G * 129 * 4);
    float* cntg = pooled + (size_t)G * 128;
    int* hist = (int*)alloc((size_t)N * 4);
    size_t zlen = (size_t)(p - zbeg);
    // ---- end zero-region ----
    int* row_ptr = (int*)alloc((size_t)(N + 1) * 4);
    int* partial = (int*)alloc((size_t)HB * N * 4);
    int* offt = (int*)alloc((size_t)HB * N * 4);
    float* coeffs = (float*)alloc(512 * 4);
    unsigned short* WT[6];
    for (int i = 0; i < 6; i++) WT[i] = (unsigned short*)alloc((size_t)L[i].Cout * L[i].K * 256 * 2);

    hipMemsetAsync(zbeg, 0, zlen, stream);   // fill, erec, stats4, pooled, cntg, hist
    if (N <= HMAXN) {
        k_hist<<<HB, 256, 0, stream>>>(ei, E, N, partial);
        k_hist_reduce<<<cdiv(N, 256), 256, 0, stream>>>(partial, hist, N, HB);
        k_scan<<<1, 1024, 0, stream>>>(hist, row_ptr, N);
        k_off<<<cdiv(N, 256), 256, 0, stream>>>(partial, row_ptr, offt, N, HB);
        k_scatter2<<<HB, 256, 0, stream>>>(ei, E, N, hist, offt, erec, Epad);
    } else {
        k_hist_glob<<<cdiv(E, 256), 256, 0, stream>>>(ei, E, hist);
        k_scan<<<1, 1024, 0, stream>>>(hist, row_ptr, N);
        k_scatter_glob<<<cdiv(E, 256), 256, 0, stream>>>(ei, E, hist, row_ptr, fill, erec, Epad);
    }
    {
        dim3 wg(950, 6);  // 950 = cdiv(max layer total = 190*5*256, 256)
        k_wconv6<<<wg, 256, 0, stream>>>(convW[0], convW[1], convW[2], convW[3], convW[4], convW[5],
                                         WT[0], WT[1], WT[2], WT[3], WT[4], WT[5]);
    }
    k_x0<<<N, 128, 0, stream>>>(x, wide, N);

    auto prop = [&](const unsigned short* in, unsigned short* outb, float* outf,
                    const unsigned short* tm2b, const float* tm2f, int Cin, int ld4) {
        int C4 = cdiv(Cin, 4);
        int gslog = (C4 <= 32) ? 5 : 6;
        int npb = 256 >> gslog;
        k_prop_w<<<cdiv(N, npb), 256, 0, stream>>>(in, outb, outf, tm2b, tm2f, row_ptr,
                                                   erec, C4, N, ld4, gslog);
    };

    for (int li = 0; li < 6; li++) {
        const int K = L[li].K, Cin = L[li].Cin, Cout = L[li].Cout;
        const int st = stride[li], ld4 = st / 4;
        const unsigned short* src = (li == 4) ? (const unsigned short*)Yb : wide;  // L5 reads Yb-as-bf16

        if (K >= 2)  // T1 = prop(T0)
            prop(src, wide + 256, (li == 3) ? B1f : nullptr, nullptr, nullptr, Cin, ld4);
        if (K >= 3)  // T2 = 2*prop(T1) - T0
            prop(wide + 256, wide + 512, (li == 3) ? B2f : nullptr, wide, nullptr, Cin, ld4);
        if (li == 3) {
            // T3 = 2*prop(T2) - T1 (fp32 tm2 = B1f; overwrite B1f with T3 fp32)
            prop(wide + 512, wide + 768, B1f, nullptr, B1f, Cin, ld4);
            // T4 = 2*prop(T3) - T2 (fp32 tm2 = B2f)
            prop(wide + 768, wide + 1024, nullptr, nullptr, B2f, Cin, ld4);
        }

        const int bnidx = L[li].bn;
        dim3 gg(cdiv(Cout, 128), cdiv(N, 128));
        if (bnidx >= 0) {
            float* stats = stats4 + bnidx * 512;   // pre-zeroed by the launch-wide memset
            k_gemm_w<<<gg, 256, 0, stream>>>(src, st, WT[li], convB[li], Yb, stats,
                                             nullptr, 0, N, st, Cout);
            k_coeffs<<<1, 256, 0, stream>>>(stats, bnW[bnidx], bnB[bnidx], bnMS[bnidx], coeffs, N, Cout);
            const int nxt = (li < 5) ? stride[li + 1] : 256;
            k_act<<<N, 256, 0, stream>>>(Yb, wide, nxt, coeffs, Cout);
        } else if (li == 3) {
            // fused ReLU -> Yb-as-bf16 (stride 256) = L5's input; cols 190..255 zero-filled
            k_gemm_w<<<gg, 256, 0, stream>>>(wide, st, WT[li], convB[li], nullptr, nullptr,
                                             (unsigned short*)Yb, 256, N, st, Cout);
        } else {
            // li==4: fused ReLU -> wide (stride 768) = L6's T0 (reads Yb, writes wide: no alias)
            k_gemm_w<<<gg, 256, 0, stream>>>((const unsigned short*)Yb, st, WT[li], convB[li],
                                             nullptr, nullptr, wide, stride[5], N, st, Cout);
        }
    }

    k_pool3<<<cdiv(N, 32), 128, 0, stream>>>(wide, batch, pooled, cntg, N);
    k_head<<<G, 128, 0, stream>>>(pooled, cntg, lin1w, lin1b, lin2w, lin2b, out);
}

// Round 13
// 949.149 us; speedup vs baseline: 1.0255x; 1.0255x over previous
//
#include <hip/hip_runtime.h>
#include <math.h>

static inline int cdiv(int a, int b) { return (a + b - 1) / b; }

typedef __attribute__((ext_vector_type(8))) short short8;
typedef __attribute__((ext_vector_type(4))) float floatx4;
typedef unsigned short ushort4e __attribute__((ext_vector_type(4)));

#define HMAXN 30720   // static LDS table capacity (N=30000 fits; 122880 B < 160 KiB)
#define HB 128        // histogram / scatter blocks (identical edge slicing)

__device__ inline unsigned short f2bf(float f) {
    unsigned int u = __float_as_uint(f);
    unsigned int r = (u + 0x7fffu + ((u >> 16) & 1u)) >> 16;
    return (unsigned short)r;
}
__device__ inline float bf2f(unsigned short u) {
    return __uint_as_float(((unsigned int)u) << 16);
}

// ---------------- CSR build (atomic-free scatter via per-block LDS offset tables) ----------------

__global__ __launch_bounds__(256) void k_hist(const int* __restrict__ ei, int E, int N,
                                              int* __restrict__ partial) {
    __shared__ int h[HMAXN];
    for (int i = threadIdx.x; i < N; i += 256) h[i] = 0;
    __syncthreads();
    int per = (E + gridDim.x - 1) / gridDim.x;
    int beg = blockIdx.x * per;
    int end = beg + per; if (end > E) end = E;
    for (int e = beg + threadIdx.x; e < end; e += 256) {
        int s = ei[e], d = ei[E + e];
        atomicAdd(&h[d], 1);                       // in-degree (cnt)
        if (s != d) atomicAdd(&h[s], 0x10000);     // out-degree excluding self (deg)
    }
    __syncthreads();
    int* outp = partial + (size_t)blockIdx.x * N;
    for (int i = threadIdx.x; i < N; i += 256) outp[i] = h[i];
}

__global__ __launch_bounds__(256) void k_hist_glob(const int* __restrict__ ei, int E,
                                                   int* __restrict__ hist) {
    int e = blockIdx.x * 256 + threadIdx.x;
    if (e >= E) return;
    int s = ei[e], d = ei[E + e];
    atomicAdd(&hist[d], 1);
    if (s != d) atomicAdd(&hist[s], 0x10000);
}

__global__ __launch_bounds__(256) void k_hist_reduce(const int* __restrict__ partial,
                                                     int* __restrict__ hist, int N, int B) {
    int i = blockIdx.x * 256 + threadIdx.x;
    if (i >= N) return;
    int s = 0;
    for (int b = 0; b < B; b++) s += partial[(size_t)b * N + i];
    hist[i] = s;
}

// padded scan: segments rounded to x8 (dummy edges = zero records -> contribute +0.0)
__global__ __launch_bounds__(1024) void k_scan(const int* __restrict__ hist, int* __restrict__ row_ptr,
                                               int N) {
    __shared__ int part[1024];
    int t = threadIdx.x;
    int chunk = (N + 1023) / 1024;
    int beg = t * chunk;
    int end = beg + chunk; if (end > N) end = N;
    int s = 0;
    for (int i = beg; i < end; i++) s += ((hist[i] & 0xffff) + 7) & ~7;
    part[t] = s;
    __syncthreads();
    for (int off = 1; off < 1024; off <<= 1) {
        int v = (t >= off) ? part[t - off] : 0;
        __syncthreads();
        part[t] += v;
        __syncthreads();
    }
    int base = (t > 0) ? part[t - 1] : 0;
    for (int i = beg; i < end; i++) { row_ptr[i] = base; base += ((hist[i] & 0xffff) + 7) & ~7; }
    if (t == 1023) row_ptr[N] = part[1023];
}

__global__ __launch_bounds__(256) void k_off(const int* __restrict__ partial,
                                             const int* __restrict__ row_ptr,
                                             int* __restrict__ off, int N, int B) {
    int i = blockIdx.x * 256 + threadIdx.x;
    if (i >= N) return;
    int run = row_ptr[i];
    for (int b = 0; b < B; b++) {
        off[(size_t)b * N + i] = run;
        run += partial[(size_t)b * N + i] & 0xffff;
    }
}

__global__ __launch_bounds__(256) void k_scatter2(const int* __restrict__ ei, int E, int N,
                                                  const int* __restrict__ hist,
                                                  const int* __restrict__ off,
                                                  int2* __restrict__ erec, int Epad) {
    __shared__ int h[HMAXN];
    const int* offb = off + (size_t)blockIdx.x * N;
    for (int i = threadIdx.x; i < N; i += 256) h[i] = offb[i];
    __syncthreads();
    int per = (E + gridDim.x - 1) / gridDim.x;
    int beg = blockIdx.x * per;
    int end = beg + per; if (end > E) end = E;
    for (int e = beg + threadIdx.x; e < end; e += 256) {
        int s = ei[e], d = ei[E + e];
        float v = 0.f;
        if (s != d) {
            int a = hist[s] >> 16, b = hist[d] >> 16;
            float fa = (a > 0) ? 1.f / sqrtf((float)a) : 0.f;
            float fb = (b > 0) ? 1.f / sqrtf((float)b) : 0.f;
            v = -fa * fb;
        }
        int pos = atomicAdd(&h[d], 1);   // LDS atomic
        if (pos < Epad) erec[pos] = make_int2(s, __float_as_int(v));
    }
}

__global__ __launch_bounds__(256) void k_scatter_glob(const int* __restrict__ ei, int E,
                                                      const int* __restrict__ hist,
                                                      const int* __restrict__ row_ptr,
                                                      int* __restrict__ fill,
                                                      int2* __restrict__ erec, int Epad) {
    int e = blockIdx.x * 256 + threadIdx.x;
    if (e >= E) return;
    int s = ei[e], d = ei[E + e];
    float v = 0.f;
    if (s != d) {
        int a = hist[s] >> 16, b = hist[d] >> 16;
        float fa = (a > 0) ? 1.f / sqrtf((float)a) : 0.f;
        float fb = (b > 0) ? 1.f / sqrtf((float)b) : 0.f;
        v = -fa * fb;
    }
    int pos = row_ptr[d] + atomicAdd(&fill[d], 1);
    if (pos < Epad) erec[pos] = make_int2(s, __float_as_int(v));
}

// -------- weight convert, all 6 layers in one dispatch --------
// W[K][Cin][Cout] fp32 -> WT[Cout][K*slot] bf16, slot = ceil(Cin/32)*32 (k zero-padded to slot)

__global__ __launch_bounds__(256) void k_wconv6(const float* __restrict__ W0, const float* __restrict__ W1,
                                                const float* __restrict__ W2, const float* __restrict__ W3,
                                                const float* __restrict__ W4, const float* __restrict__ W5,
                                                unsigned short* __restrict__ T0, unsigned short* __restrict__ T1,
                                                unsigned short* __restrict__ T2, unsigned short* __restrict__ T3,
                                                unsigned short* __restrict__ T4, unsigned short* __restrict__ T5) {
    const int Cin[6]  = {128, 190, 256, 169, 190, 256};
    const int Cout[6] = {190, 256, 169, 190, 256, 128};
    const int Kt[6]   = {2, 2, 2, 5, 1, 3};
    const int Slot[6] = {128, 192, 256, 192, 192, 256};
    const float* Ws[6] = {W0, W1, W2, W3, W4, W5};
    unsigned short* Ts[6] = {T0, T1, T2, T3, T4, T5};
    int li = blockIdx.y;
    int sl = Slot[li];
    int ldk = Kt[li] * sl;
    int total = Cout[li] * ldk;
    int idx = blockIdx.x * 256 + threadIdx.x;
    if (idx >= total) return;
    int n = idx / ldk;
    int rem = idx - n * ldk;
    int term = rem / sl;
    int k = rem - term * sl;
    float v = (k < Cin[li]) ? Ws[li][(size_t)term * Cin[li] * Cout[li] + (size_t)k * Cout[li] + n] : 0.f;
    Ts[li][idx] = f2bf(v);
}

// ---------------- x (fp32, ld 128) -> wide bf16, stride 256, cols 0..127 ----------------

__global__ __launch_bounds__(128) void k_x0(const float* __restrict__ x, unsigned short* __restrict__ xb, int N) {
    int n = blockIdx.x;
    int c = threadIdx.x;
    xb[(size_t)n * 256 + c] = f2bf(x[(size_t)n * 128 + c]);
}

// ---------------- wave-per-node propagation (bf16 gather, fp32 accumulate) ----------------
// C4 = slot/4 so slot pads (zeros in the source) propagate as exact zeros.

__global__ __launch_bounds__(256) void k_prop_w(const unsigned short* __restrict__ in,
                                                unsigned short* __restrict__ outb,
                                                float* __restrict__ outf,
                                                const unsigned short* __restrict__ tm2b,
                                                const float* __restrict__ tm2f,
                                                const int* __restrict__ row_ptr,
                                                const int2* __restrict__ erec,
                                                int C4, int Nn, int ld4, int gslog) {
    const int node = blockIdx.x * (256 >> gslog) + (threadIdx.x >> gslog);
    if (node >= Nn) return;
    const int lane4 = threadIdx.x & ((1 << gslog) - 1);
    if (lane4 >= C4) return;

    int beg = row_ptr[node], end = row_ptr[node + 1];
    const ushort4e* h4 = (const ushort4e*)in;
    float a0 = 0.f, a1 = 0.f, a2 = 0.f, a3 = 0.f;
    for (int j = beg; j < end; j += 8) {
        int4 r0 = *(const int4*)&erec[j];
        int4 r1 = *(const int4*)&erec[j + 2];
        int4 r2 = *(const int4*)&erec[j + 4];
        int4 r3 = *(const int4*)&erec[j + 6];
        ushort4e v0 = h4[(size_t)r0.x * ld4 + lane4];
        ushort4e v1 = h4[(size_t)r0.z * ld4 + lane4];
        ushort4e v2 = h4[(size_t)r1.x * ld4 + lane4];
        ushort4e v3 = h4[(size_t)r1.z * ld4 + lane4];
        ushort4e v4 = h4[(size_t)r2.x * ld4 + lane4];
        ushort4e v5 = h4[(size_t)r2.z * ld4 + lane4];
        ushort4e v6 = h4[(size_t)r3.x * ld4 + lane4];
        ushort4e v7 = h4[(size_t)r3.z * ld4 + lane4];
        float n0 = __int_as_float(r0.y), n1 = __int_as_float(r0.w);
        float n2 = __int_as_float(r1.y), n3 = __int_as_float(r1.w);
        float n4 = __int_as_float(r2.y), n5 = __int_as_float(r2.w);
        float n6 = __int_as_float(r3.y), n7 = __int_as_float(r3.w);
        a0 += n0 * bf2f(v0.x) + n1 * bf2f(v1.x) + n2 * bf2f(v2.x) + n3 * bf2f(v3.x)
            + n4 * bf2f(v4.x) + n5 * bf2f(v5.x) + n6 * bf2f(v6.x) + n7 * bf2f(v7.x);
        a1 += n0 * bf2f(v0.y) + n1 * bf2f(v1.y) + n2 * bf2f(v2.y) + n3 * bf2f(v3.y)
            + n4 * bf2f(v4.y) + n5 * bf2f(v5.y) + n6 * bf2f(v6.y) + n7 * bf2f(v7.y);
        a2 += n0 * bf2f(v0.z) + n1 * bf2f(v1.z) + n2 * bf2f(v2.z) + n3 * bf2f(v3.z)
            + n4 * bf2f(v4.z) + n5 * bf2f(v5.z) + n6 * bf2f(v6.z) + n7 * bf2f(v7.z);
        a3 += n0 * bf2f(v0.w) + n1 * bf2f(v1.w) + n2 * bf2f(v2.w) + n3 * bf2f(v3.w)
            + n4 * bf2f(v4.w) + n5 * bf2f(v5.w) + n6 * bf2f(v6.w) + n7 * bf2f(v7.w);
    }
    if (tm2b) {
        ushort4e t = ((const ushort4e*)tm2b)[(size_t)node * ld4 + lane4];
        a0 = 2.f * a0 - bf2f(t.x); a1 = 2.f * a1 - bf2f(t.y);
        a2 = 2.f * a2 - bf2f(t.z); a3 = 2.f * a3 - bf2f(t.w);
    } else if (tm2f) {
        float4 t = ((const float4*)tm2f)[(size_t)node * 48 + lane4];
        a0 = 2.f * a0 - t.x; a1 = 2.f * a1 - t.y; a2 = 2.f * a2 - t.z; a3 = 2.f * a3 - t.w;
    }
    ushort4e r;
    r.x = f2bf(a0); r.y = f2bf(a1); r.z = f2bf(a2); r.w = f2bf(a3);
    ((ushort4e*)outb)[(size_t)node * ld4 + lane4] = r;
    if (outf) ((float4*)outf)[(size_t)node * 48 + lane4] = make_float4(a0, a1, a2, a3);
}

// ------- wide bf16 MFMA GEMM: A(bf16, lda) @ WT^T + bias -------
// stats path: Y fp32 (stride 256) + fused column sum/sumsq.
// fused-ReLU path: bf16 to hb at stride ldo; cols [Cout, cpad) written as EXACT ZEROS
// (downstream GEMM reading the padded K-region must never see bf16-NaN garbage).

__global__ __launch_bounds__(256, 2) void k_gemm_w(const unsigned short* __restrict__ A, int lda,
                                                   const unsigned short* __restrict__ WT,
                                                   const float* __restrict__ bias,
                                                   float* __restrict__ Y,
                                                   float* __restrict__ stats,
                                                   unsigned short* __restrict__ hb, int ldo, int cpad,
                                                   int M, int Kp, int Cout) {
    __shared__ unsigned short As[128][40];
    __shared__ unsigned short Bs[128][40];
    const int t = threadIdx.x;
    const int bm = blockIdx.y * 128, bn = blockIdx.x * 128;
    const int w = t >> 6, lane = t & 63;
    const int wr = w >> 1, wc = w & 1;
    const int fr = lane & 15, fg = lane >> 4;
    const int srow = t >> 2;
    const int skq = (t & 3) * 8;

    floatx4 acc[4][4];
#pragma unroll
    for (int i = 0; i < 4; i++)
#pragma unroll
        for (int j = 0; j < 4; j++) acc[i][j] = (floatx4){0.f, 0.f, 0.f, 0.f};

    for (int k0 = 0; k0 < Kp; k0 += 32) {
#pragma unroll
        for (int p = 0; p < 2; p++) {
            int r = p * 64 + srow;
            int grow = bm + r;
            uint4 av = make_uint4(0u, 0u, 0u, 0u);
            if (grow < M) av = *(const uint4*)&A[(size_t)grow * lda + k0 + skq];
            *(uint4*)&As[r][skq] = av;
            int gn = bn + r;
            uint4 bv = make_uint4(0u, 0u, 0u, 0u);
            if (gn < Cout) bv = *(const uint4*)&WT[(size_t)gn * lda + k0 + skq];
            *(uint4*)&Bs[r][skq] = bv;
        }
        __syncthreads();

        short8 a[4], b[4];
#pragma unroll
        for (int i = 0; i < 4; i++) a[i] = *(const short8*)&As[64 * wr + 16 * i + fr][fg * 8];
#pragma unroll
        for (int j = 0; j < 4; j++) b[j] = *(const short8*)&Bs[64 * wc + 16 * j + fr][fg * 8];
#pragma unroll
        for (int i = 0; i < 4; i++)
#pragma unroll
            for (int j = 0; j < 4; j++)
                acc[i][j] = __builtin_amdgcn_mfma_f32_16x16x32_bf16(a[i], b[j], acc[i][j], 0, 0, 0);
        __syncthreads();
    }

    // epilogue: C/D layout col=lane&15, row=(lane>>4)*4+q
    if (stats) {
        float s1[4] = {0.f, 0.f, 0.f, 0.f};
        float s2[4] = {0.f, 0.f, 0.f, 0.f};
#pragma unroll
        for (int j = 0; j < 4; j++) {
            int c = bn + 64 * wc + 16 * j + fr;
#pragma unroll
            for (int i = 0; i < 4; i++) {
#pragma unroll
                for (int q = 0; q < 4; q++) {
                    int r = bm + 64 * wr + 16 * i + fg * 4 + q;
                    float v = 0.f;
                    if (r < M && c < Cout) {
                        v = acc[i][j][q] + bias[c];
                        Y[(size_t)r * 256 + c] = v;
                    }
                    s1[j] += v;
                    s2[j] += v * v;
                }
            }
        }
#pragma unroll
        for (int j = 0; j < 4; j++) {
            s1[j] += __shfl_xor(s1[j], 16, 64);
            s1[j] += __shfl_xor(s1[j], 32, 64);
            s2[j] += __shfl_xor(s2[j], 16, 64);
            s2[j] += __shfl_xor(s2[j], 32, 64);
            if (fg == 0) {
                int c = bn + 64 * wc + 16 * j + fr;
                if (c < Cout) {
                    atomicAdd(&stats[c], s1[j]);
                    atomicAdd(&stats[256 + c], s2[j]);
                }
            }
        }
    } else {
        // fused ReLU -> bf16; zero-fill cols [Cout, cpad); never write c >= cpad (row bound)
#pragma unroll
        for (int j = 0; j < 4; j++) {
            int c = bn + 64 * wc + 16 * j + fr;
            if (c >= cpad) continue;
            float bc = (c < Cout) ? bias[c] : 0.f;
#pragma unroll
            for (int i = 0; i < 4; i++) {
#pragma unroll
                for (int q = 0; q < 4; q++) {
                    int r = bm + 64 * wr + 16 * i + fg * 4 + q;
                    if (r < M) {
                        float v = (c < Cout) ? fmaxf(acc[i][j][q] + bc, 0.f) : 0.f;
                        hb[(size_t)r * ldo + c] = f2bf(v);
                    }
                }
            }
        }
    }
}

// ---------------- GraphNorm coeffs ----------------

__global__ __launch_bounds__(256) void k_coeffs(const float* __restrict__ stats,
                                                const float* __restrict__ w, const float* __restrict__ b,
                                                const float* __restrict__ ms,
                                                float* __restrict__ coeffs, int N, int C) {
    int c = threadIdx.x;
    if (c >= C) return;
    float m = stats[c] / (float)N;
    float q = stats[256 + c] / (float)N;
    float msv = ms[c];
    float v = q - m * m * msv * (2.f - msv);
    float sc = w[c] / sqrtf(v + 1e-5f);
    coeffs[c] = sc;
    coeffs[256 + c] = b[c] - sc * m * msv;
}

// leaky(0.2) + GraphNorm affine; reads Yb (fp32, stride 256), writes bf16 at stride ldo,
// zero-filling slot pad cols [C, Cpad)
__global__ __launch_bounds__(256) void k_act(const float* __restrict__ Y, unsigned short* __restrict__ hb,
                                             int ldo, const float* __restrict__ coeffs, int C, int Cpad) {
    int n = blockIdx.x;
    int c = threadIdx.x;
    if (c >= Cpad) return;
    float v = 0.f;
    if (c < C) {
        v = Y[(size_t)n * 256 + c];
        v = v * coeffs[c] + coeffs[256 + c];
        v = (v > 0.f) ? v : 0.2f * v;
    }
    hb[(size_t)n * ldo + c] = f2bf(v);
}

// ---------------- pooling (sorted batch -> segmented run reduction, stride 128) + head --------

__global__ __launch_bounds__(128) void k_pool3(const unsigned short* __restrict__ hb, const int* __restrict__ batch,
                                               float* __restrict__ pooled, float* __restrict__ cntg, int N) {
    int t = threadIdx.x;
    int beg = blockIdx.x * 32;
    int end = beg + 32; if (end > N) end = N;
    if (beg >= N) return;
    int cur = batch[beg];
    float acc = 0.f;
    int runlen = 0;
    for (int n = beg; n < end; n++) {
        int b = batch[n];
        if (b != cur) {
            atomicAdd(&pooled[cur * 128 + t], acc);
            if (t == 0) atomicAdd(&cntg[cur], (float)runlen);
            acc = 0.f; runlen = 0; cur = b;
        }
        acc += bf2f(hb[(size_t)n * 128 + t]);
        runlen++;
    }
    atomicAdd(&pooled[cur * 128 + t], acc);
    if (t == 0) atomicAdd(&cntg[cur], (float)runlen);
}

__global__ __launch_bounds__(128) void k_head(const float* __restrict__ pooled, const float* __restrict__ cntg,
                                              const float* __restrict__ W1, const float* __restrict__ b1,
                                              const float* __restrict__ W2, const float* __restrict__ b2,
                                              float* __restrict__ out) {
    __shared__ float p[128];
    __shared__ float h1[64];
    int g = blockIdx.x;
    int t = threadIdx.x;
    float c = cntg[g];
    if (c < 1.f) c = 1.f;
    p[t] = pooled[g * 128 + t] / c;
    __syncthreads();
    if (t < 64) {
        float s = b1[t];
        for (int i = 0; i < 128; i++) s += p[i] * W1[i * 64 + t];
        h1[t] = tanhf(s);
    }
    __syncthreads();
    if (t < 10) {
        float s = b2[t];
        for (int i = 0; i < 64; i++) s += h1[i] * W2[i * 10 + t];
        out[g * 10 + t] = s;
    }
}

// ---------------- orchestration ----------------

extern "C" void kernel_launch(void* const* d_in, const int* in_sizes, int n_in,
                              void* d_out, int out_size, void* d_ws, size_t ws_size,
                              hipStream_t stream) {
    const float* x = (const float*)d_in[0];
    const int* ei = (const int*)d_in[1];
    const int* batch = (const int*)d_in[2];
    const float* convW[6]; const float* convB[6];
    for (int i = 0; i < 6; i++) { convW[i] = (const float*)d_in[3 + 2 * i]; convB[i] = (const float*)d_in[4 + 2 * i]; }
    const float* bnW[4]; const float* bnB[4]; const float* bnMS[4];
    for (int i = 0; i < 4; i++) { bnW[i] = (const float*)d_in[15 + 3 * i]; bnB[i] = (const float*)d_in[16 + 3 * i]; bnMS[i] = (const float*)d_in[17 + 3 * i]; }
    const float* lin1w = (const float*)d_in[27]; const float* lin1b = (const float*)d_in[28];
    const float* lin2w = (const float*)d_in[29]; const float* lin2b = (const float*)d_in[30];
    float* out = (float*)d_out;

    const int N = in_sizes[0] / 128;
    const int E = in_sizes[1] / 2;
    const int G = out_size / 10;
    const int Epad = E + 8 * N;

    struct LayerDef { int K, Cin, Cout, bn; };
    const LayerDef L[6] = {
        {2, 128, 190, 0},
        {2, 190, 256, 1},
        {2, 256, 169, 2},
        {5, 169, 190, -1},
        {1, 190, 256, -1},
        {3, 256, 128, 3},
    };
    const int slot[6]   = {128, 192, 256, 192, 192, 256};   // ceil(Cin/32)*32
    const int stride[6] = {256, 384, 512, 960, 192, 768};   // K * slot

    char* p = (char*)d_ws;
    auto alloc = [&](size_t bytes) -> void* { void* r = (void*)p; p += (bytes + 255) & ~(size_t)255; return r; };
    unsigned short* wide = (unsigned short*)alloc((size_t)N * 960 * 2);   // all Chebyshev terms, bf16
    float* Yb  = (float*)alloc((size_t)N * 256 * 4);                      // GN-layer GEMM out; doubles as L4->L5 bf16 buf
    float* B1f = (float*)alloc((size_t)N * 192 * 4);                      // fp32 tm2 copies (layer 4)
    float* B2f = (float*)alloc((size_t)N * 192 * 4);
    // ---- contiguous zero-region (single memset at launch start) ----
    char* zbeg = p;
    int* fill = (int*)alloc((size_t)N * 4);                // used only by fallback path
    int2* erec = (int2*)alloc((size_t)Epad * 8);           // interleaved (src, norm) records
    float* stats4 = (float*)alloc(4 * 512 * 4);            // per-GN-layer stats slices
    float* pooled = (float*)alloc((size_t)G * 129 * 4);
    float* cntg = pooled + (size_t)G * 128;
    int* hist = (int*)alloc((size_t)N * 4);
    size_t zlen = (size_t)(p - zbeg);
    // ---- end zero-region ----
    int* row_ptr = (int*)alloc((size_t)(N + 1) * 4);
    int* partial = (int*)alloc((size_t)HB * N * 4);
    int* offt = (int*)alloc((size_t)HB * N * 4);
    float* coeffs = (float*)alloc(512 * 4);
    unsigned short* WT[6];
    for (int i = 0; i < 6; i++) WT[i] = (unsigned short*)alloc((size_t)L[i].Cout * stride[i] * 2);

    hipMemsetAsync(zbeg, 0, zlen, stream);   // fill, erec, stats4, pooled, cntg, hist
    if (N <= HMAXN) {
        k_hist<<<HB, 256, 0, stream>>>(ei, E, N, partial);
        k_hist_reduce<<<cdiv(N, 256), 256, 0, stream>>>(partial, hist, N, HB);
        k_scan<<<1, 1024, 0, stream>>>(hist, row_ptr, N);
        k_off<<<cdiv(N, 256), 256, 0, stream>>>(partial, row_ptr, offt, N, HB);
        k_scatter2<<<HB, 256, 0, stream>>>(ei, E, N, hist, offt, erec, Epad);
    } else {
        k_hist_glob<<<cdiv(E, 256), 256, 0, stream>>>(ei, E, hist);
        k_scan<<<1, 1024, 0, stream>>>(hist, row_ptr, N);
        k_scatter_glob<<<cdiv(E, 256), 256, 0, stream>>>(ei, E, hist, row_ptr, fill, erec, Epad);
    }
    {
        dim3 wg(713, 6);  // 713 = cdiv(max layer total = 190*960, 256)
        k_wconv6<<<wg, 256, 0, stream>>>(convW[0], convW[1], convW[2], convW[3], convW[4], convW[5],
                                         WT[0], WT[1], WT[2], WT[3], WT[4], WT[5]);
    }
    k_x0<<<N, 128, 0, stream>>>(x, wide, N);

    auto prop = [&](const unsigned short* in, unsigned short* outb, float* outf,
                    const unsigned short* tm2b, const float* tm2f, int C4, int ld4) {
        int gslog = (C4 <= 32) ? 5 : 6;
        int npb = 256 >> gslog;
        k_prop_w<<<cdiv(N, npb), 256, 0, stream>>>(in, outb, outf, tm2b, tm2f, row_ptr,
                                                   erec, C4, N, ld4, gslog);
    };

    for (int li = 0; li < 6; li++) {
        const int K = L[li].K, Cout = L[li].Cout;
        const int st = stride[li], ld4 = st / 4;
        const int sl = slot[li], C4 = sl / 4;
        const unsigned short* src = (li == 4) ? (const unsigned short*)Yb : wide;  // L5 reads Yb-as-bf16

        if (K >= 2)  // T1 = prop(T0)
            prop(src, wide + sl, (li == 3) ? B1f : nullptr, nullptr, nullptr, C4, ld4);
        if (K >= 3)  // T2 = 2*prop(T1) - T0
            prop(wide + sl, wide + 2 * sl, (li == 3) ? B2f : nullptr, wide, nullptr, C4, ld4);
        if (li == 3) {
            // T3 = 2*prop(T2) - T1 (fp32 tm2 = B1f; overwrite B1f with T3 fp32)
            prop(wide + 2 * sl, wide + 3 * sl, B1f, nullptr, B1f, C4, ld4);
            // T4 = 2*prop(T3) - T2 (fp32 tm2 = B2f)
            prop(wide + 3 * sl, wide + 4 * sl, nullptr, nullptr, B2f, C4, ld4);
        }

        const int bnidx = L[li].bn;
        dim3 gg(cdiv(Cout, 128), cdiv(N, 128));
        if (bnidx >= 0) {
            float* stats = stats4 + bnidx * 512;   // pre-zeroed by the launch-wide memset
            k_gemm_w<<<gg, 256, 0, stream>>>(src, st, WT[li], convB[li], Yb, stats,
                                             nullptr, 0, 0, N, st, Cout);
            k_coeffs<<<1, 256, 0, stream>>>(stats, bnW[bnidx], bnB[bnidx], bnMS[bnidx], coeffs, N, Cout);
            // act writes NEXT layer's T0 slot (zero-filling slot pad); last layer -> stride 128
            const int nxt_ld = (li < 5) ? stride[li + 1] : 128;
            const int nxt_cp = (li < 5) ? slot[li + 1] : 128;
            k_act<<<N, 256, 0, stream>>>(Yb, wide, nxt_ld, coeffs, Cout, nxt_cp);
        } else if (li == 3) {
            // fused ReLU -> Yb-as-bf16 at L5's stride 192; cols 190..191 zero-filled
            k_gemm_w<<<gg, 256, 0, stream>>>(wide, st, WT[li], convB[li], nullptr, nullptr,
                                             (unsigned short*)Yb, stride[4], slot[4], N, st, Cout);
        } else {
            // li==4: fused ReLU -> wide stride 768 = L6's T0 (slot 256, Cout 256: no pad)
            k_gemm_w<<<gg, 256, 0, stream>>>((const unsigned short*)Yb, st, WT[li], convB[li],
                                             nullptr, nullptr, wide, stride[5], slot[5], N, st, Cout);
        }
    }

    k_pool3<<<cdiv(N, 32), 128, 0, stream>>>(wide, batch, pooled, cntg, N);
    k_head<<<G, 128, 0, stream>>>(pooled, cntg, lin1w, lin1b, lin2w, lin2b, out);
}